// Round 8
// baseline (3596.996 us; speedup 1.0000x reference)
//
#include <hip/hip_runtime.h>
#include <hip/hip_bf16.h>

#define T_STEPS 48
#define B_SZ    64
#define H_IN    64
#define W_IN    64
#define OC      16
#define KH      7
#define KW      7
#define STRIDEC 2
#define HO      29
#define WO      29
#define IN_SZ   13456
#define N_NEU   1000
#define N_PAD   1024

// ---------------- ws layout (bytes) ----------------
#define WT_OFF    0ull                 // WlsmT padded [1000][1024] f32 = 4,096,000
#define CURR_OFF  4096000ull           // curr [48][64][1024] f32 = 12,582,912
#define SYN_OFF   16678912ull          // [64][1024] f32 = 262,144
#define MEM_OFF   16941056ull          // [64][1024] f32 = 262,144
#define MASK_OFF  17203200ull          // 2 x [64][16] u64 = 16,384
#define G_OFF     17219584ull          // conv output buffer

// ---------------- Wlsm transpose: WT[m][n] = Wlsm[n][m], zero-pad n>=1000 ----
__global__ __launch_bounds__(256) void transpose_wlsm(const float* __restrict__ Wlsm,
                                                      float* __restrict__ WT) {
  __shared__ float t[32][33];
  const int m0 = blockIdx.x * 32;
  const int n0 = blockIdx.y * 32;
  const int tx = threadIdx.x & 31, ty = threadIdx.x >> 5;  // 32 x 8
  #pragma unroll
  for (int j = 0; j < 4; ++j) {
    int n = n0 + ty + j * 8, m = m0 + tx;
    t[ty + j * 8][tx] = (n < N_NEU && m < N_NEU) ? Wlsm[n * N_NEU + m] : 0.f;
  }
  __syncthreads();
  #pragma unroll
  for (int j = 0; j < 4; ++j) {
    int m = m0 + ty + j * 8, n = n0 + tx;
    if (m < N_NEU) WT[(size_t)m * N_PAD + n] = t[tx][ty + j * 8];
  }
}

// ---------------- Gabor conv: one block per image (verbatim) ----------------
__global__ __launch_bounds__(256) void conv_kernel(const float* __restrict__ x,
                                                   const float* __restrict__ w,
                                                   float* __restrict__ g,
                                                   int img0) {
  __shared__ float img[H_IN * W_IN];
  const int blk = blockIdx.x;
  const float* xim = x + (size_t)(img0 + blk) * (H_IN * W_IN);
  for (int i = threadIdx.x; i < (H_IN * W_IN) / 4; i += 256)
    ((float4*)img)[i] = ((const float4*)xim)[i];
  __syncthreads();
  float* gout = g + (size_t)blk * IN_SZ;
  for (int pos = threadIdx.x; pos < HO * WO; pos += 256) {
    const int oh = pos / WO, ow = pos - oh * WO;
    const int ih = oh * STRIDEC, iw = ow * STRIDEC;
    float acc[OC];
    #pragma unroll
    for (int oc = 0; oc < OC; ++oc) acc[oc] = 0.f;
    #pragma unroll
    for (int kh = 0; kh < KH; ++kh) {
      #pragma unroll
      for (int kw = 0; kw < KW; ++kw) {
        const float v = img[(ih + kh) * W_IN + iw + kw];
        const int widx = kh * KW + kw;
        #pragma unroll
        for (int oc = 0; oc < OC; ++oc)
          acc[oc] += v * w[oc * (KH * KW) + widx];
      }
    }
    #pragma unroll
    for (int oc = 0; oc < OC; ++oc)
      gout[oc * (HO * WO) + pos] = acc[oc];
  }
}

// ---------------- fp32 GEMM v4: R7 math (bit-identical), double-buffered ----
// Per output (r,c): for k0 = 0,32,...: lacc = sum_{kk} A[r][k0+kk]*B[c][k0+kk],
// acc += lacc; out = acc + bias. Same chain as R7 (PASSED). New: reg-staged
// LDS double buffer, one barrier per k-tile, global latency hidden under compute.
#define BM3 128
#define BN3 64
#define BK3 32
#define LDA3 132
#define LDB3 68
#define NT3 421   // ceil(13456/32)

__device__ __forceinline__ void gemm_load(const float* __restrict__ A,
                                          const float* __restrict__ Bp,
                                          int row_l0, int n0, int k0, int tid,
                                          float4* rva, float4* rvb) {
  #pragma unroll
  for (int it = 0; it < 4; ++it) {
    const int f = it * 256 + tid;
    const int rr = f >> 3;
    const int kq = (f & 7) * 4;
    const int k = k0 + kq;
    float4 v = make_float4(0.f, 0.f, 0.f, 0.f);
    if (k < IN_SZ)  // k, IN_SZ multiples of 4 -> full quad in range
      v = *(const float4*)(A + (size_t)(row_l0 + rr) * IN_SZ + k);
    rva[it] = v;
  }
  #pragma unroll
  for (int it = 0; it < 2; ++it) {
    const int f = it * 256 + tid;
    const int cc = f >> 3;
    const int kq = (f & 7) * 4;
    const int k = k0 + kq;
    float4 v = make_float4(0.f, 0.f, 0.f, 0.f);
    if (k < IN_SZ && n0 + cc < N_NEU)
      v = *(const float4*)(Bp + (size_t)(n0 + cc) * IN_SZ + k);
    rvb[it] = v;
  }
}

__device__ __forceinline__ void gemm_write(float* __restrict__ as,
                                           float* __restrict__ bs, int tid,
                                           const float4* rva, const float4* rvb) {
  #pragma unroll
  for (int it = 0; it < 4; ++it) {
    const int f = it * 256 + tid;
    const int rr = f >> 3;
    const int kq = (f & 7) * 4;
    as[(kq + 0) * LDA3 + rr] = rva[it].x;
    as[(kq + 1) * LDA3 + rr] = rva[it].y;
    as[(kq + 2) * LDA3 + rr] = rva[it].z;
    as[(kq + 3) * LDA3 + rr] = rva[it].w;
  }
  #pragma unroll
  for (int it = 0; it < 2; ++it) {
    const int f = it * 256 + tid;
    const int cc = f >> 3;
    const int kq = (f & 7) * 4;
    bs[(kq + 0) * LDB3 + cc] = rvb[it].x;
    bs[(kq + 1) * LDB3 + cc] = rvb[it].y;
    bs[(kq + 2) * LDB3 + cc] = rvb[it].z;
    bs[(kq + 3) * LDB3 + cc] = rvb[it].w;
  }
}

__global__ __launch_bounds__(256) void gemm_kernel(const float* __restrict__ A,
                                                   int row_off,
                                                   const float* __restrict__ Wins,
                                                   const float* __restrict__ fc1_b,
                                                   float* __restrict__ curr) {
  __shared__ __align__(16) float As[2][BK3 * LDA3];
  __shared__ __align__(16) float Bs[2][BK3 * LDB3];
  const int tid = threadIdx.x;
  const int n0 = blockIdx.x * BN3;
  const int row_l0 = blockIdx.y * BM3;
  const int r0 = (tid >> 4) * 8;
  const int c0 = (tid & 15) * 4;
  const int p = (row_off + row_l0) / 768;
  const float* Bp = Wins + (size_t)p * N_NEU * IN_SZ;

  float4 rva[4], rvb[2];
  float acc[8][4];
  #pragma unroll
  for (int i = 0; i < 8; ++i)
    #pragma unroll
    for (int j = 0; j < 4; ++j) acc[i][j] = 0.f;

  gemm_load(A, Bp, row_l0, n0, 0, tid, rva, rvb);
  gemm_write(As[0], Bs[0], tid, rva, rvb);
  __syncthreads();
  int cur = 0;

  for (int t = 0; t < NT3; ++t) {
    if (t + 1 < NT3)  // issue next tile's global loads early (hidden by compute)
      gemm_load(A, Bp, row_l0, n0, (t + 1) * BK3, tid, rva, rvb);

    const float* as = As[cur];
    const float* bs = Bs[cur];
    float lacc[8][4];
    #pragma unroll
    for (int i = 0; i < 8; ++i)
      #pragma unroll
      for (int j = 0; j < 4; ++j) lacc[i][j] = 0.f;
    #pragma unroll
    for (int kk = 0; kk < BK3; ++kk) {
      const float4 a0 = *(const float4*)&as[kk * LDA3 + r0];
      const float4 a1 = *(const float4*)&as[kk * LDA3 + r0 + 4];
      const float4 b0 = *(const float4*)&bs[kk * LDB3 + c0];
      const float a[8] = {a0.x, a0.y, a0.z, a0.w, a1.x, a1.y, a1.z, a1.w};
      const float bb[4] = {b0.x, b0.y, b0.z, b0.w};
      #pragma unroll
      for (int i = 0; i < 8; ++i)
        #pragma unroll
        for (int j = 0; j < 4; ++j) lacc[i][j] += a[i] * bb[j];
    }
    #pragma unroll
    for (int i = 0; i < 8; ++i)
      #pragma unroll
      for (int j = 0; j < 4; ++j) acc[i][j] += lacc[i][j];

    if (t + 1 < NT3) {
      gemm_write(As[cur ^ 1], Bs[cur ^ 1], tid, rva, rvb);
      __syncthreads();
      cur ^= 1;
    }
  }

  const int g_row_base = row_off + row_l0 + r0;
  #pragma unroll
  for (int i = 0; i < 8; ++i) {
    float* crow = curr + ((size_t)(g_row_base + i) << 10);
    float4 o;
    const int nn = n0 + c0;
    o.x = acc[i][0] + fc1_b[nn + 0 < N_NEU ? nn + 0 : (N_NEU - 1)];
    o.y = acc[i][1] + fc1_b[nn + 1 < N_NEU ? nn + 1 : (N_NEU - 1)];
    o.z = acc[i][2] + fc1_b[nn + 2 < N_NEU ? nn + 2 : (N_NEU - 1)];
    o.w = acc[i][3] + fc1_b[nn + 3 < N_NEU ? nn + 3 : (N_NEU - 1)];
    *(float4*)(crow + nn) = o;
  }
}

// ---------------- one recurrence step, block-local; 4-deep load ILP ---------
// Summation order identical to R6/R7 (ascending j within group, then groups).
__global__ __launch_bounds__(256) void step_kernel(
    const float* __restrict__ WT, const float* __restrict__ curr_t,
    const float* __restrict__ rec_b, float* __restrict__ syn,
    float* __restrict__ mem_s, const unsigned long long* __restrict__ mask_rd,
    unsigned long long* __restrict__ mask_wr, float* __restrict__ out_t) {
  __shared__ int idxs[1024];
  __shared__ int cnts[16];
  __shared__ int offs[17];
  __shared__ float4 red[256];
  __shared__ unsigned char nib[32];
  const int tid = threadIdx.x;
  const int b = blockIdx.x >> 3;
  const int e = blockIdx.x & 7;       // n-eighth: n in [e*128, e*128+128)

  if (tid < 16) cnts[tid] = (int)__popcll(mask_rd[(b << 4) | tid]);
  __syncthreads();
  if (tid == 0) {
    int o = 0;
    #pragma unroll
    for (int c = 0; c < 16; ++c) { offs[c] = o; o += cnts[c]; }
    offs[16] = o;
  }
  __syncthreads();
  if (tid < 16) {
    unsigned long long s = mask_rd[(b << 4) | tid];
    int o = offs[tid];
    const int base = tid << 6;
    while (s) {
      idxs[o++] = base + __builtin_ctzll(s);
      s &= s - 1;
    }
  }
  __syncthreads();
  const int L = offs[16];

  const int g = tid >> 5;
  const int ln = tid & 31;
  const float* wc = WT + e * 128 + ln * 4;
  float4 acc = make_float4(0.f, 0.f, 0.f, 0.f);
  int j = g;
  for (; j + 32 <= L; j += 32) {
    const float4 v0 = *(const float4*)(wc + ((size_t)idxs[j] << 10));
    const float4 v1 = *(const float4*)(wc + ((size_t)idxs[j + 8] << 10));
    const float4 v2 = *(const float4*)(wc + ((size_t)idxs[j + 16] << 10));
    const float4 v3 = *(const float4*)(wc + ((size_t)idxs[j + 24] << 10));
    acc.x += v0.x; acc.y += v0.y; acc.z += v0.z; acc.w += v0.w;
    acc.x += v1.x; acc.y += v1.y; acc.z += v1.z; acc.w += v1.w;
    acc.x += v2.x; acc.y += v2.y; acc.z += v2.z; acc.w += v2.w;
    acc.x += v3.x; acc.y += v3.y; acc.z += v3.z; acc.w += v3.w;
  }
  for (; j + 16 <= L; j += 16) {
    const float4 v0 = *(const float4*)(wc + ((size_t)idxs[j] << 10));
    const float4 v1 = *(const float4*)(wc + ((size_t)idxs[j + 8] << 10));
    acc.x += v0.x; acc.y += v0.y; acc.z += v0.z; acc.w += v0.w;
    acc.x += v1.x; acc.y += v1.y; acc.z += v1.z; acc.w += v1.w;
  }
  for (; j < L; j += 8) {
    const float4 v = *(const float4*)(wc + ((size_t)idxs[j] << 10));
    acc.x += v.x; acc.y += v.y; acc.z += v.z; acc.w += v.w;
  }
  red[tid] = acc;
  __syncthreads();

  if (tid < 32) {
    float4 rec = red[tid];
    #pragma unroll
    for (int h = 1; h < 8; ++h) {
      const float4 v = red[h * 32 + tid];
      rec.x += v.x; rec.y += v.y; rec.z += v.z; rec.w += v.w;
    }
    const int n = e * 128 + tid * 4;
    const size_t idx = ((size_t)b << 10) + n;
    const float4 cv = *(const float4*)(curr_t + idx);
    float4 sv = *(float4*)(syn + idx);
    float4 mv = *(float4*)(mem_s + idx);
    const float rb0 = (n + 0 < N_NEU) ? rec_b[n + 0] : 0.f;
    const float rb1 = (n + 1 < N_NEU) ? rec_b[n + 1] : 0.f;
    const float rb2 = (n + 2 < N_NEU) ? rec_b[n + 2] : 0.f;
    const float rb3 = (n + 3 < N_NEU) ? rec_b[n + 3] : 0.f;
    float4 sn, mn;
    sn.x = 0.9f * sv.x + cv.x + rec.x + rb0;
    sn.y = 0.9f * sv.y + cv.y + rec.y + rb1;
    sn.z = 0.9f * sv.z + cv.z + rec.z + rb2;
    sn.w = 0.9f * sv.w + cv.w + rec.w + rb3;
    mn.x = 0.9f * mv.x + sn.x - ((mv.x - 1.0f > 0.f) ? 1.0f : 0.f);
    mn.y = 0.9f * mv.y + sn.y - ((mv.y - 1.0f > 0.f) ? 1.0f : 0.f);
    mn.z = 0.9f * mv.z + sn.z - ((mv.z - 1.0f > 0.f) ? 1.0f : 0.f);
    mn.w = 0.9f * mv.w + sn.w - ((mv.w - 1.0f > 0.f) ? 1.0f : 0.f);
    *(float4*)(syn + idx) = sn;
    *(float4*)(mem_s + idx) = mn;
    const int s0 = ((mn.x - 1.0f) > 0.f && n + 0 < N_NEU) ? 1 : 0;
    const int s1 = ((mn.y - 1.0f) > 0.f && n + 1 < N_NEU) ? 1 : 0;
    const int s2 = ((mn.z - 1.0f) > 0.f && n + 2 < N_NEU) ? 1 : 0;
    const int s3 = ((mn.w - 1.0f) > 0.f && n + 3 < N_NEU) ? 1 : 0;
    if (n + 0 < N_NEU) out_t[b * N_NEU + n + 0] = (float)s0;
    if (n + 1 < N_NEU) out_t[b * N_NEU + n + 1] = (float)s1;
    if (n + 2 < N_NEU) out_t[b * N_NEU + n + 2] = (float)s2;
    if (n + 3 < N_NEU) out_t[b * N_NEU + n + 3] = (float)s3;
    nib[tid] = (unsigned char)(s0 | (s1 << 1) | (s2 << 2) | (s3 << 3));
  }
  __syncthreads();
  if (tid < 2) {
    unsigned long long w = 0;
    #pragma unroll
    for (int i = 0; i < 16; ++i)
      w |= (unsigned long long)nib[tid * 16 + i] << (4 * i);
    mask_wr[(b << 4) | (e * 2 + tid)] = w;
  }
}

extern "C" void kernel_launch(void* const* d_in, const int* in_sizes, int n_in,
                              void* d_out, int out_size, void* d_ws, size_t ws_size,
                              hipStream_t stream) {
  const float* x     = (const float*)d_in[0];
  const float* gw    = (const float*)d_in[1];
  const float* Wins  = (const float*)d_in[2];
  const float* fc1_b = (const float*)d_in[3];
  const float* Wlsm  = (const float*)d_in[4];
  const float* rec_b = (const float*)d_in[5];
  float* out = (float*)d_out;
  char* ws = (char*)d_ws;

  float* WT   = (float*)(ws + WT_OFF);
  float* curr = (float*)(ws + CURR_OFF);
  float* syn  = (float*)(ws + SYN_OFF);
  float* mem  = (float*)(ws + MEM_OFF);
  unsigned long long* mask = (unsigned long long*)(ws + MASK_OFF);
  float* gbuf = (float*)(ws + G_OFF);

  // zero state: syn, mem, both mask buffers (contiguous region)
  (void)hipMemsetAsync(ws + SYN_OFF, 0, (size_t)(MASK_OFF - SYN_OFF) + 16384, stream);

  hipLaunchKernelGGL(transpose_wlsm, dim3(32, 32), dim3(256), 0, stream, Wlsm, WT);

  const size_t needA = G_OFF + (size_t)3072 * IN_SZ * 4;
  if (ws_size >= needA) {
    hipLaunchKernelGGL(conv_kernel, dim3(3072), dim3(256), 0, stream, x, gw, gbuf, 0);
    hipLaunchKernelGGL(gemm_kernel, dim3(16, 24), dim3(256), 0, stream,
                       gbuf, 0, Wins, fc1_b, curr);
  } else {
    for (int p = 0; p < 4; ++p) {
      hipLaunchKernelGGL(conv_kernel, dim3(768), dim3(256), 0, stream,
                         x, gw, gbuf, p * 768);
      hipLaunchKernelGGL(gemm_kernel, dim3(16, 6), dim3(256), 0, stream,
                         gbuf, p * 768, Wins, fc1_b, curr);
    }
  }

  for (int t = 0; t < T_STEPS; ++t) {
    hipLaunchKernelGGL(step_kernel, dim3(512), dim3(256), 0, stream,
                       WT, curr + (size_t)t * 65536, rec_b, syn, mem,
                       mask + (size_t)(t & 1) * 1024,
                       mask + (size_t)((t + 1) & 1) * 1024,
                       out + (size_t)t * 64000);
  }
}

// Round 9
// 2536.032 us; speedup vs baseline: 1.4184x; 1.4184x over previous
//
#include <hip/hip_runtime.h>
#include <hip/hip_bf16.h>

#define T_STEPS 48
#define B_SZ    64
#define H_IN    64
#define W_IN    64
#define OC      16
#define KH      7
#define KW      7
#define STRIDEC 2
#define HO      29
#define WO      29
#define IN_SZ   13456
#define N_NEU   1000
#define N_PAD   1024

// ---------------- ws layout (bytes) ----------------
#define WT_OFF    0ull                 // WlsmT padded [1000][1024] f32 = 4,096,000
#define CURR_OFF  4096000ull           // curr [48][64][1024] f32 = 12,582,912
#define SYN_OFF   16678912ull          // [64][1024] f32 = 262,144
#define MEM_OFF   16941056ull          // [64][1024] f32 = 262,144
#define MASK_OFF  17203200ull          // 2 x [64][16] u64 = 16,384
#define G_OFF     17219584ull          // conv output buffer

// ---------------- Wlsm transpose: WT[m][n] = Wlsm[n][m], zero-pad n>=1000 ----
__global__ __launch_bounds__(256) void transpose_wlsm(const float* __restrict__ Wlsm,
                                                      float* __restrict__ WT) {
  __shared__ float t[32][33];
  const int m0 = blockIdx.x * 32;
  const int n0 = blockIdx.y * 32;
  const int tx = threadIdx.x & 31, ty = threadIdx.x >> 5;  // 32 x 8
  #pragma unroll
  for (int j = 0; j < 4; ++j) {
    int n = n0 + ty + j * 8, m = m0 + tx;
    t[ty + j * 8][tx] = (n < N_NEU && m < N_NEU) ? Wlsm[n * N_NEU + m] : 0.f;
  }
  __syncthreads();
  #pragma unroll
  for (int j = 0; j < 4; ++j) {
    int m = m0 + ty + j * 8, n = n0 + tx;
    if (m < N_NEU) WT[(size_t)m * N_PAD + n] = t[tx][ty + j * 8];
  }
}

// ---------------- Gabor conv: one block per image (verbatim) ----------------
__global__ __launch_bounds__(256) void conv_kernel(const float* __restrict__ x,
                                                   const float* __restrict__ w,
                                                   float* __restrict__ g,
                                                   int img0) {
  __shared__ float img[H_IN * W_IN];
  const int blk = blockIdx.x;
  const float* xim = x + (size_t)(img0 + blk) * (H_IN * W_IN);
  for (int i = threadIdx.x; i < (H_IN * W_IN) / 4; i += 256)
    ((float4*)img)[i] = ((const float4*)xim)[i];
  __syncthreads();
  float* gout = g + (size_t)blk * IN_SZ;
  for (int pos = threadIdx.x; pos < HO * WO; pos += 256) {
    const int oh = pos / WO, ow = pos - oh * WO;
    const int ih = oh * STRIDEC, iw = ow * STRIDEC;
    float acc[OC];
    #pragma unroll
    for (int oc = 0; oc < OC; ++oc) acc[oc] = 0.f;
    #pragma unroll
    for (int kh = 0; kh < KH; ++kh) {
      #pragma unroll
      for (int kw = 0; kw < KW; ++kw) {
        const float v = img[(ih + kh) * W_IN + iw + kw];
        const int widx = kh * KW + kw;
        #pragma unroll
        for (int oc = 0; oc < OC; ++oc)
          acc[oc] += v * w[oc * (KH * KW) + widx];
      }
    }
    #pragma unroll
    for (int oc = 0; oc < OC; ++oc)
      gout[oc * (HO * WO) + pos] = acc[oc];
  }
}

// ---------------- fp32 GEMM v5: R7 single-buffer structure, 64x64 tile ------
// Per output (r,c): for k0 = 0,32,...: lacc = sum_{kk} A[r][k0+kk]*B[c][k0+kk]
// (fma chain kk ascending), acc += lacc; out = acc + bias. Bit-identical chain
// to R1/R7 (PASSED). Tile 64x64, micro 4x4, grid (16,48)=768 blocks = 3/CU.
#define BM5 64
#define BN5 64
#define BK5 32
#define LDA5 68
#define LDB5 68
__global__ __launch_bounds__(256) void gemm_kernel(const float* __restrict__ A,
                                                   int row_off,
                                                   const float* __restrict__ Wins,
                                                   const float* __restrict__ fc1_b,
                                                   float* __restrict__ curr) {
  __shared__ __align__(16) float As[BK5 * LDA5];
  __shared__ __align__(16) float Bs[BK5 * LDB5];
  const int tid = threadIdx.x;
  const int n0 = blockIdx.x * BN5;            // 16 n-tiles
  const int row_l0 = blockIdx.y * BM5;        // 48 m-tiles
  const int r0 = (tid >> 4) * 4;              // 16 row-groups of 4
  const int c0 = (tid & 15) * 4;              // 16 col-groups of 4
  const int p = (row_off + row_l0) / 768;
  const float* Bp = Wins + (size_t)p * N_NEU * IN_SZ;

  float acc[4][4];
  #pragma unroll
  for (int i = 0; i < 4; ++i)
    #pragma unroll
    for (int j = 0; j < 4; ++j) acc[i][j] = 0.f;

  for (int k0 = 0; k0 < IN_SZ; k0 += BK5) {
    // stage A: 64 rows x 32 k (k-major)
    #pragma unroll
    for (int it = 0; it < 2; ++it) {
      const int f = it * 256 + tid;     // [0,512)
      const int rr = f >> 3;            // [0,64)
      const int kq = (f & 7) * 4;       // {0,4,...,28}
      const int k = k0 + kq;
      float4 va = make_float4(0.f, 0.f, 0.f, 0.f);
      if (k < IN_SZ)   // k, IN_SZ multiples of 4 -> full quad in range
        va = *(const float4*)(A + (size_t)(row_l0 + rr) * IN_SZ + k);
      As[(kq + 0) * LDA5 + rr] = va.x;
      As[(kq + 1) * LDA5 + rr] = va.y;
      As[(kq + 2) * LDA5 + rr] = va.z;
      As[(kq + 3) * LDA5 + rr] = va.w;
    }
    // stage B: 64 cols x 32 k (k-major)
    #pragma unroll
    for (int it = 0; it < 2; ++it) {
      const int f = it * 256 + tid;     // [0,512)
      const int cc = f >> 3;            // [0,64)
      const int kq = (f & 7) * 4;
      const int k = k0 + kq;
      float4 vb = make_float4(0.f, 0.f, 0.f, 0.f);
      if (k < IN_SZ && n0 + cc < N_NEU)
        vb = *(const float4*)(Bp + (size_t)(n0 + cc) * IN_SZ + k);
      Bs[(kq + 0) * LDB5 + cc] = vb.x;
      Bs[(kq + 1) * LDB5 + cc] = vb.y;
      Bs[(kq + 2) * LDB5 + cc] = vb.z;
      Bs[(kq + 3) * LDB5 + cc] = vb.w;
    }
    __syncthreads();

    float lacc[4][4];
    #pragma unroll
    for (int i = 0; i < 4; ++i)
      #pragma unroll
      for (int j = 0; j < 4; ++j) lacc[i][j] = 0.f;
    #pragma unroll
    for (int kk = 0; kk < BK5; ++kk) {
      const float4 a0 = *(const float4*)&As[kk * LDA5 + r0];
      const float4 b0 = *(const float4*)&Bs[kk * LDB5 + c0];
      const float a[4] = {a0.x, a0.y, a0.z, a0.w};
      const float bb[4] = {b0.x, b0.y, b0.z, b0.w};
      #pragma unroll
      for (int i = 0; i < 4; ++i)
        #pragma unroll
        for (int j = 0; j < 4; ++j) lacc[i][j] += a[i] * bb[j];
    }
    #pragma unroll
    for (int i = 0; i < 4; ++i)
      #pragma unroll
      for (int j = 0; j < 4; ++j) acc[i][j] += lacc[i][j];
    __syncthreads();
  }

  const int g_row_base = row_off + row_l0 + r0;
  #pragma unroll
  for (int i = 0; i < 4; ++i) {
    float* crow = curr + ((size_t)(g_row_base + i) << 10);
    float4 o;
    const int nn = n0 + c0;
    o.x = acc[i][0] + fc1_b[nn + 0 < N_NEU ? nn + 0 : (N_NEU - 1)];
    o.y = acc[i][1] + fc1_b[nn + 1 < N_NEU ? nn + 1 : (N_NEU - 1)];
    o.z = acc[i][2] + fc1_b[nn + 2 < N_NEU ? nn + 2 : (N_NEU - 1)];
    o.w = acc[i][3] + fc1_b[nn + 3 < N_NEU ? nn + 3 : (N_NEU - 1)];
    *(float4*)(crow + nn) = o;
  }
}

// ---------------- one recurrence step, block-local; 4-deep load ILP ---------
__global__ __launch_bounds__(256) void step_kernel(
    const float* __restrict__ WT, const float* __restrict__ curr_t,
    const float* __restrict__ rec_b, float* __restrict__ syn,
    float* __restrict__ mem_s, const unsigned long long* __restrict__ mask_rd,
    unsigned long long* __restrict__ mask_wr, float* __restrict__ out_t) {
  __shared__ int idxs[1024];
  __shared__ int cnts[16];
  __shared__ int offs[17];
  __shared__ float4 red[256];
  __shared__ unsigned char nib[32];
  const int tid = threadIdx.x;
  const int b = blockIdx.x >> 3;
  const int e = blockIdx.x & 7;       // n-eighth: n in [e*128, e*128+128)

  if (tid < 16) cnts[tid] = (int)__popcll(mask_rd[(b << 4) | tid]);
  __syncthreads();
  if (tid == 0) {
    int o = 0;
    #pragma unroll
    for (int c = 0; c < 16; ++c) { offs[c] = o; o += cnts[c]; }
    offs[16] = o;
  }
  __syncthreads();
  if (tid < 16) {
    unsigned long long s = mask_rd[(b << 4) | tid];
    int o = offs[tid];
    const int base = tid << 6;
    while (s) {
      idxs[o++] = base + __builtin_ctzll(s);
      s &= s - 1;
    }
  }
  __syncthreads();
  const int L = offs[16];

  const int g = tid >> 5;
  const int ln = tid & 31;
  const float* wc = WT + e * 128 + ln * 4;
  float4 acc = make_float4(0.f, 0.f, 0.f, 0.f);
  int j = g;
  for (; j + 32 <= L; j += 32) {
    const float4 v0 = *(const float4*)(wc + ((size_t)idxs[j] << 10));
    const float4 v1 = *(const float4*)(wc + ((size_t)idxs[j + 8] << 10));
    const float4 v2 = *(const float4*)(wc + ((size_t)idxs[j + 16] << 10));
    const float4 v3 = *(const float4*)(wc + ((size_t)idxs[j + 24] << 10));
    acc.x += v0.x; acc.y += v0.y; acc.z += v0.z; acc.w += v0.w;
    acc.x += v1.x; acc.y += v1.y; acc.z += v1.z; acc.w += v1.w;
    acc.x += v2.x; acc.y += v2.y; acc.z += v2.z; acc.w += v2.w;
    acc.x += v3.x; acc.y += v3.y; acc.z += v3.z; acc.w += v3.w;
  }
  for (; j + 16 <= L; j += 16) {
    const float4 v0 = *(const float4*)(wc + ((size_t)idxs[j] << 10));
    const float4 v1 = *(const float4*)(wc + ((size_t)idxs[j + 8] << 10));
    acc.x += v0.x; acc.y += v0.y; acc.z += v0.z; acc.w += v0.w;
    acc.x += v1.x; acc.y += v1.y; acc.z += v1.z; acc.w += v1.w;
  }
  for (; j < L; j += 8) {
    const float4 v = *(const float4*)(wc + ((size_t)idxs[j] << 10));
    acc.x += v.x; acc.y += v.y; acc.z += v.z; acc.w += v.w;
  }
  red[tid] = acc;
  __syncthreads();

  if (tid < 32) {
    float4 rec = red[tid];
    #pragma unroll
    for (int h = 1; h < 8; ++h) {
      const float4 v = red[h * 32 + tid];
      rec.x += v.x; rec.y += v.y; rec.z += v.z; rec.w += v.w;
    }
    const int n = e * 128 + tid * 4;
    const size_t idx = ((size_t)b << 10) + n;
    const float4 cv = *(const float4*)(curr_t + idx);
    float4 sv = *(float4*)(syn + idx);
    float4 mv = *(float4*)(mem_s + idx);
    const float rb0 = (n + 0 < N_NEU) ? rec_b[n + 0] : 0.f;
    const float rb1 = (n + 1 < N_NEU) ? rec_b[n + 1] : 0.f;
    const float rb2 = (n + 2 < N_NEU) ? rec_b[n + 2] : 0.f;
    const float rb3 = (n + 3 < N_NEU) ? rec_b[n + 3] : 0.f;
    float4 sn, mn;
    sn.x = 0.9f * sv.x + cv.x + rec.x + rb0;
    sn.y = 0.9f * sv.y + cv.y + rec.y + rb1;
    sn.z = 0.9f * sv.z + cv.z + rec.z + rb2;
    sn.w = 0.9f * sv.w + cv.w + rec.w + rb3;
    mn.x = 0.9f * mv.x + sn.x - ((mv.x - 1.0f > 0.f) ? 1.0f : 0.f);
    mn.y = 0.9f * mv.y + sn.y - ((mv.y - 1.0f > 0.f) ? 1.0f : 0.f);
    mn.z = 0.9f * mv.z + sn.z - ((mv.z - 1.0f > 0.f) ? 1.0f : 0.f);
    mn.w = 0.9f * mv.w + sn.w - ((mv.w - 1.0f > 0.f) ? 1.0f : 0.f);
    *(float4*)(syn + idx) = sn;
    *(float4*)(mem_s + idx) = mn;
    const int s0 = ((mn.x - 1.0f) > 0.f && n + 0 < N_NEU) ? 1 : 0;
    const int s1 = ((mn.y - 1.0f) > 0.f && n + 1 < N_NEU) ? 1 : 0;
    const int s2 = ((mn.z - 1.0f) > 0.f && n + 2 < N_NEU) ? 1 : 0;
    const int s3 = ((mn.w - 1.0f) > 0.f && n + 3 < N_NEU) ? 1 : 0;
    if (n + 0 < N_NEU) out_t[b * N_NEU + n + 0] = (float)s0;
    if (n + 1 < N_NEU) out_t[b * N_NEU + n + 1] = (float)s1;
    if (n + 2 < N_NEU) out_t[b * N_NEU + n + 2] = (float)s2;
    if (n + 3 < N_NEU) out_t[b * N_NEU + n + 3] = (float)s3;
    nib[tid] = (unsigned char)(s0 | (s1 << 1) | (s2 << 2) | (s3 << 3));
  }
  __syncthreads();
  if (tid < 2) {
    unsigned long long w = 0;
    #pragma unroll
    for (int i = 0; i < 16; ++i)
      w |= (unsigned long long)nib[tid * 16 + i] << (4 * i);
    mask_wr[(b << 4) | (e * 2 + tid)] = w;
  }
}

extern "C" void kernel_launch(void* const* d_in, const int* in_sizes, int n_in,
                              void* d_out, int out_size, void* d_ws, size_t ws_size,
                              hipStream_t stream) {
  const float* x     = (const float*)d_in[0];
  const float* gw    = (const float*)d_in[1];
  const float* Wins  = (const float*)d_in[2];
  const float* fc1_b = (const float*)d_in[3];
  const float* Wlsm  = (const float*)d_in[4];
  const float* rec_b = (const float*)d_in[5];
  float* out = (float*)d_out;
  char* ws = (char*)d_ws;

  float* WT   = (float*)(ws + WT_OFF);
  float* curr = (float*)(ws + CURR_OFF);
  float* syn  = (float*)(ws + SYN_OFF);
  float* mem  = (float*)(ws + MEM_OFF);
  unsigned long long* mask = (unsigned long long*)(ws + MASK_OFF);
  float* gbuf = (float*)(ws + G_OFF);

  // zero state: syn, mem, both mask buffers (contiguous region)
  (void)hipMemsetAsync(ws + SYN_OFF, 0, (size_t)(MASK_OFF - SYN_OFF) + 16384, stream);

  hipLaunchKernelGGL(transpose_wlsm, dim3(32, 32), dim3(256), 0, stream, Wlsm, WT);

  const size_t needA = G_OFF + (size_t)3072 * IN_SZ * 4;
  if (ws_size >= needA) {
    hipLaunchKernelGGL(conv_kernel, dim3(3072), dim3(256), 0, stream, x, gw, gbuf, 0);
    hipLaunchKernelGGL(gemm_kernel, dim3(16, 48), dim3(256), 0, stream,
                       gbuf, 0, Wins, fc1_b, curr);
  } else {
    for (int p = 0; p < 4; ++p) {
      hipLaunchKernelGGL(conv_kernel, dim3(768), dim3(256), 0, stream,
                         x, gw, gbuf, p * 768);
      hipLaunchKernelGGL(gemm_kernel, dim3(16, 12), dim3(256), 0, stream,
                         gbuf, p * 768, Wins, fc1_b, curr);
    }
  }

  for (int t = 0; t < T_STEPS; ++t) {
    hipLaunchKernelGGL(step_kernel, dim3(512), dim3(256), 0, stream,
                       WT, curr + (size_t)t * 65536, rec_b, syn, mem,
                       mask + (size_t)(t & 1) * 1024,
                       mask + (size_t)((t + 1) & 1) * 1024,
                       out + (size_t)t * 64000);
  }
}